// Round 1
// baseline (741.649 us; speedup 1.0000x reference)
//
#include <hip/hip_runtime.h>

// ---------- problem constants ----------
#define BB 4096
#define NN 25
#define DD 256
#define HH 8
#define DKH 32
#define MM (BB*NN)          // 102400

typedef __bf16 bf16;
typedef bf16 bf16x8 __attribute__((ext_vector_type(8)));
typedef bf16 bf16x4 __attribute__((ext_vector_type(4)));
typedef float f32x4 __attribute__((ext_vector_type(4)));

// async global->LDS, 16B per lane, LDS dest = wave-uniform base + lane*16
__device__ __forceinline__ void async_load16(const bf16* g, bf16* l) {
  __builtin_amdgcn_global_load_lds(
      (const __attribute__((address_space(1))) unsigned int*)(const void*)g,
      (__attribute__((address_space(3))) unsigned int*)(void*)l, 16, 0, 0);
}

// ---------- prep: padded bf16 x  x_pad[b][j][d], j in [0,27): j=0,26 zero, else x[b][j-1][d]
__global__ __launch_bounds__(256) void k_prep_xpad(const float* __restrict__ x,
                                                   bf16* __restrict__ xpad) {
  int idx = (blockIdx.x * 256 + threadIdx.x) * 8;
  const int total = BB * 27 * 256;
  if (idx >= total) return;
  int b = idx / (27 * 256);
  int rem = idx - b * 27 * 256;
  int j = rem >> 8;
  int d = rem & 255;
  bf16x8 o;
  if (j >= 1 && j <= 25) {
    const float* src = x + ((b * 25 + (j - 1)) * 256 + d);
    #pragma unroll
    for (int t = 0; t < 8; ++t) o[t] = (bf16)src[t];
  } else {
    #pragma unroll
    for (int t = 0; t < 8; ++t) o[t] = (bf16)0.0f;
  }
  *(bf16x8*)(xpad + idx) = o;
}

// ---------- prep: Wt[768][768] (B^T for qkv gemm), wo bf16, combined bias, adj mask ----------
__global__ __launch_bounds__(256) void k_prep_misc(
    const float* __restrict__ wq, const float* __restrict__ wk, const float* __restrict__ wv,
    const float* __restrict__ rel, const float* __restrict__ lb, const float* __restrict__ wo,
    const void* __restrict__ adj_raw,
    bf16* __restrict__ Wt, bf16* __restrict__ woB, float* __restrict__ bias,
    int* __restrict__ adjm) {
  const int NWT = 768 * 768;
  const int NWO = 256 * 256;
  const int NBIAS = HH * NN * NN;
  const int NADJ = NN * NN;
  const int total = NWT + NWO + NBIAS + NADJ;
  for (int i = blockIdx.x * blockDim.x + threadIdx.x; i < total; i += gridDim.x * blockDim.x) {
    if (i < NWT) {
      int j = i / 768, kk = i - j * 768;
      int proj = j >> 8, jo = j & 255;
      int tap = kk >> 8, di = kk & 255;
      const float* w = (proj == 0) ? wq : ((proj == 1) ? wk : wv);
      Wt[i] = (bf16)w[(jo * 256 + di) * 3 + tap];   // w[d_out][d_in][tap]
    } else if (i < NWT + NWO) {
      int t = i - NWT;
      woB[t] = (bf16)wo[t];                          // wo[j][d] is already B^T layout
    } else if (i < NWT + NWO + NBIAS) {
      int t = i - NWT - NWO;
      int h = t / 625, r = t - h * 625;
      int ii = r / 25, mm2 = r - ii * 25;
      bias[t] = rel[(ii - mm2 + 24) * HH + h] + lb[t];
    } else {
      int t = i - NWT - NWO - NBIAS;
      // detect whether adj is uint8 (bool) or int32: nonzero byte at offset%4!=0 => uint8
      const unsigned char* bytes = (const unsigned char*)adj_raw;
      bool u8 = false;
      for (int s = 0; s < 625; ++s) {
        if ((s & 3) && bytes[s]) { u8 = true; break; }
      }
      int v = u8 ? (bytes[t] ? 1 : 0) : (((const int*)adj_raw)[t] ? 1 : 0);
      adjm[t] = v;
    }
  }
}

// ---------- QKV GEMM: C[102400][768] = A_gather[102400][768] * Wt^T, bf16 MFMA ----------
__global__ __launch_bounds__(256) void k_qkv_gemm(const bf16* __restrict__ xpad,
                                                  const bf16* __restrict__ Wt,
                                                  bf16* __restrict__ conv) {
  __shared__ bf16 As[128 * 32];
  __shared__ bf16 Bs[128 * 32];
  const int m0 = blockIdx.x * 128;
  const int n0 = blockIdx.y * 128;
  const int tid = threadIdx.x;
  const int wave = tid >> 6, lane = tid & 63;
  const int quad = lane >> 4, t16 = lane & 15;
  const int wr = wave >> 1, wc = wave & 1;

  f32x4 acc[4][4];
  #pragma unroll
  for (int i = 0; i < 4; ++i)
    #pragma unroll
    for (int j = 0; j < 4; ++j) acc[i][j] = (f32x4){0.f, 0.f, 0.f, 0.f};

  // hoisted staging bases (row/sub fixed per thread per round)
  const bf16* baseA[2];
  const bf16* baseB[2];
  #pragma unroll
  for (int r = 0; r < 2; ++r) {
    int c = r * 256 + wave * 64 + lane;
    int row = c >> 2, sub = c & 3;
    int gm = m0 + row;
    int b = gm / 25;
    int n = gm - b * 25;
    baseA[r] = xpad + (b * 27 + n) * 256 + sub * 8;
    baseB[r] = Wt + (n0 + row) * 768 + sub * 8;
  }

  for (int ks = 0; ks < 768; ks += 32) {
    const int tap = ks >> 8;
    const int d0 = ks & 255;
    #pragma unroll
    for (int r = 0; r < 2; ++r)
      async_load16(baseA[r] + tap * 256 + d0, As + (r * 256 + wave * 64) * 8);
    #pragma unroll
    for (int r = 0; r < 2; ++r)
      async_load16(baseB[r] + ks, Bs + (r * 256 + wave * 64) * 8);
    asm volatile("s_waitcnt vmcnt(0)" ::: "memory");
    __syncthreads();

    bf16x8 af[4], bfr[4];
    #pragma unroll
    for (int i = 0; i < 4; ++i)
      af[i] = *(const bf16x8*)(As + (wr * 64 + i * 16 + t16) * 32 + quad * 8);
    #pragma unroll
    for (int j = 0; j < 4; ++j)
      bfr[j] = *(const bf16x8*)(Bs + (wc * 64 + j * 16 + t16) * 32 + quad * 8);
    #pragma unroll
    for (int i = 0; i < 4; ++i)
      #pragma unroll
      for (int j = 0; j < 4; ++j)
        acc[i][j] = __builtin_amdgcn_mfma_f32_16x16x32_bf16(af[i], bfr[j], acc[i][j], 0, 0, 0);
    __syncthreads();
  }

  // epilogue: C/D layout col=lane&15, row=quad*4+r
  #pragma unroll
  for (int i = 0; i < 4; ++i)
    #pragma unroll
    for (int j = 0; j < 4; ++j) {
      int col = n0 + wc * 64 + j * 16 + t16;
      #pragma unroll
      for (int r = 0; r < 4; ++r) {
        int rowm = m0 + wr * 64 + i * 16 + quad * 4 + r;
        conv[rowm * 768 + col] = (bf16)acc[i][j][r];
      }
    }
}

// ---------- per-batch LN + residual + masked attention ----------
__global__ __launch_bounds__(256) void k_attn(
    const bf16* __restrict__ conv, const float* __restrict__ x,
    const float* __restrict__ gq, const float* __restrict__ bq,
    const float* __restrict__ gk, const float* __restrict__ bk,
    const float* __restrict__ gv, const float* __restrict__ bv,
    const float* __restrict__ bias, const int* __restrict__ adjm,
    bf16* __restrict__ attnout) {
  __shared__ float qf[25 * 256];
  __shared__ float kf[25 * 256];
  __shared__ bf16 vb[25 * 256];
  const int b = blockIdx.x;
  const int tid = threadIdx.x;
  const int wave = tid >> 6, lane = tid & 63;

  // phase 1: layernorm + residual for 75 rows (3 proj x 25 nodes), one wave per row
  for (int rowi = wave; rowi < 75; rowi += 4) {
    int p = rowi / 25;
    int n = rowi - p * 25;
    bf16x4 cv = *(const bf16x4*)(conv + (b * 25 + n) * 768 + p * 256 + lane * 4);
    float v0 = (float)cv[0], v1 = (float)cv[1], v2 = (float)cv[2], v3 = (float)cv[3];
    float s = v0 + v1 + v2 + v3;
    float ss = v0 * v0 + v1 * v1 + v2 * v2 + v3 * v3;
    #pragma unroll
    for (int off = 32; off; off >>= 1) {
      s += __shfl_xor(s, off);
      ss += __shfl_xor(ss, off);
    }
    float mu = s * (1.0f / 256.0f);
    float var = ss * (1.0f / 256.0f) - mu * mu;
    float rs = rsqrtf(var + 1e-5f);
    const float* gsel = (p == 0) ? gq : ((p == 1) ? gk : gv);
    const float* bsel = (p == 0) ? bq : ((p == 1) ? bk : bv);
    int dbase = lane * 4;
    f32x4 gg = *(const f32x4*)(gsel + dbase);
    f32x4 b2 = *(const f32x4*)(bsel + dbase);
    f32x4 xv = *(const f32x4*)(x + (b * 25 + n) * 256 + dbase);
    float y0 = (v0 - mu) * rs * gg[0] + b2[0] + xv[0];
    float y1 = (v1 - mu) * rs * gg[1] + b2[1] + xv[1];
    float y2 = (v2 - mu) * rs * gg[2] + b2[2] + xv[2];
    float y3 = (v3 - mu) * rs * gg[3] + b2[3] + xv[3];
    if (p == 0) {
      *(f32x4*)(qf + n * 256 + dbase) = (f32x4){y0, y1, y2, y3};
    } else if (p == 1) {
      *(f32x4*)(kf + n * 256 + dbase) = (f32x4){y0, y1, y2, y3};
    } else {
      bf16x4 o; o[0] = (bf16)y0; o[1] = (bf16)y1; o[2] = (bf16)y2; o[3] = (bf16)y3;
      *(bf16x4*)(vb + n * 256 + dbase) = o;
    }
  }
  __syncthreads();

  // phase 2: one lane per (head, query-node)
  if (tid < HH * NN) {
    int h = tid / 25;
    int i = tid - h * 25;
    float ql[32];
    #pragma unroll
    for (int d = 0; d < 32; d += 4) {
      f32x4 t4 = *(const f32x4*)(qf + i * 256 + h * 32 + d);
      ql[d] = t4[0]; ql[d + 1] = t4[1]; ql[d + 2] = t4[2]; ql[d + 3] = t4[3];
    }
    const float scale = 0.17677669529663687f;  // 1/sqrt(32)
    float sc[25];
    #pragma unroll
    for (int m = 0; m < 25; ++m) {
      float dot = 0.f;
      #pragma unroll
      for (int d = 0; d < 32; d += 4) {
        f32x4 k4 = *(const f32x4*)(kf + m * 256 + h * 32 + d);
        dot += ql[d] * k4[0] + ql[d + 1] * k4[1] + ql[d + 2] * k4[2] + ql[d + 3] * k4[3];
      }
      sc[m] = adjm[i * 25 + m] ? (dot * scale + bias[h * 625 + i * 25 + m]) : -1e30f;
    }
    float mx = sc[0];
    #pragma unroll
    for (int m = 1; m < 25; ++m) mx = fmaxf(mx, sc[m]);
    float sum = 0.f;
    #pragma unroll
    for (int m = 0; m < 25; ++m) { sc[m] = __expf(sc[m] - mx); sum += sc[m]; }
    float inv = 1.0f / sum;
    float acc[32];
    #pragma unroll
    for (int d = 0; d < 32; ++d) acc[d] = 0.f;
    #pragma unroll
    for (int m = 0; m < 25; ++m) {
      float w = sc[m];
      #pragma unroll
      for (int c = 0; c < 4; ++c) {
        bf16x8 v8 = *(const bf16x8*)(vb + m * 256 + h * 32 + c * 8);
        #pragma unroll
        for (int t = 0; t < 8; ++t) acc[c * 8 + t] += w * (float)v8[t];
      }
    }
    bf16* dst = attnout + (b * 25 + i) * 256 + h * 32;
    #pragma unroll
    for (int c = 0; c < 4; ++c) {
      bf16x8 o;
      #pragma unroll
      for (int t = 0; t < 8; ++t) o[t] = (bf16)(acc[c * 8 + t] * inv);
      *(bf16x8*)(dst + c * 8) = o;
    }
  }
}

// ---------- output projection: out = attn @ wo^T + bo (f32 out) ----------
__global__ __launch_bounds__(256) void k_outproj(const bf16* __restrict__ attn,
                                                 const bf16* __restrict__ woB,
                                                 const float* __restrict__ bo,
                                                 float* __restrict__ out) {
  __shared__ bf16 As[128 * 32];
  __shared__ bf16 Bs[128 * 32];
  const int m0 = blockIdx.x * 128;
  const int n0 = blockIdx.y * 128;
  const int tid = threadIdx.x;
  const int wave = tid >> 6, lane = tid & 63;
  const int quad = lane >> 4, t16 = lane & 15;
  const int wr = wave >> 1, wc = wave & 1;

  f32x4 acc[4][4];
  #pragma unroll
  for (int i = 0; i < 4; ++i)
    #pragma unroll
    for (int j = 0; j < 4; ++j) acc[i][j] = (f32x4){0.f, 0.f, 0.f, 0.f};

  const bf16* baseA[2];
  const bf16* baseB[2];
  #pragma unroll
  for (int r = 0; r < 2; ++r) {
    int c = r * 256 + wave * 64 + lane;
    int row = c >> 2, sub = c & 3;
    baseA[r] = attn + (m0 + row) * 256 + sub * 8;
    baseB[r] = woB + (n0 + row) * 256 + sub * 8;
  }

  for (int ks = 0; ks < 256; ks += 32) {
    #pragma unroll
    for (int r = 0; r < 2; ++r)
      async_load16(baseA[r] + ks, As + (r * 256 + wave * 64) * 8);
    #pragma unroll
    for (int r = 0; r < 2; ++r)
      async_load16(baseB[r] + ks, Bs + (r * 256 + wave * 64) * 8);
    asm volatile("s_waitcnt vmcnt(0)" ::: "memory");
    __syncthreads();

    bf16x8 af[4], bfr[4];
    #pragma unroll
    for (int i = 0; i < 4; ++i)
      af[i] = *(const bf16x8*)(As + (wr * 64 + i * 16 + t16) * 32 + quad * 8);
    #pragma unroll
    for (int j = 0; j < 4; ++j)
      bfr[j] = *(const bf16x8*)(Bs + (wc * 64 + j * 16 + t16) * 32 + quad * 8);
    #pragma unroll
    for (int i = 0; i < 4; ++i)
      #pragma unroll
      for (int j = 0; j < 4; ++j)
        acc[i][j] = __builtin_amdgcn_mfma_f32_16x16x32_bf16(af[i], bfr[j], acc[i][j], 0, 0, 0);
    __syncthreads();
  }

  #pragma unroll
  for (int j = 0; j < 4; ++j) {
    int col = n0 + wc * 64 + j * 16 + t16;
    float bb = bo[col];
    #pragma unroll
    for (int i = 0; i < 4; ++i)
      #pragma unroll
      for (int r = 0; r < 4; ++r) {
        int rowm = m0 + wr * 64 + i * 16 + quad * 4 + r;
        out[rowm * 256 + col] = acc[i][j][r] + bb;
      }
  }
}

extern "C" void kernel_launch(void* const* d_in, const int* in_sizes, int n_in,
                              void* d_out, int out_size, void* d_ws, size_t ws_size,
                              hipStream_t stream) {
  (void)in_sizes; (void)n_in; (void)out_size; (void)ws_size;
  const float* x  = (const float*)d_in[0];
  const void*  adj = d_in[1];
  const float* wq = (const float*)d_in[2];
  const float* wk = (const float*)d_in[3];
  const float* wv = (const float*)d_in[4];
  const float* gq = (const float*)d_in[5];
  const float* bq = (const float*)d_in[6];
  const float* gk = (const float*)d_in[7];
  const float* bk = (const float*)d_in[8];
  const float* gv = (const float*)d_in[9];
  const float* bv = (const float*)d_in[10];
  const float* rel = (const float*)d_in[11];
  const float* lb = (const float*)d_in[12];
  const float* wo = (const float*)d_in[13];
  const float* bo = (const float*)d_in[14];
  float* out = (float*)d_out;

  char* ws = (char*)d_ws;
  size_t off = 0;
  auto alloc = [&](size_t bytes) -> void* {
    void* p = ws + off;
    off += (bytes + 255) & ~(size_t)255;
    return p;
  };
  bf16* xpad = (bf16*)alloc((size_t)BB * 27 * 256 * 2);    // 56.6 MB
  bf16* conv = (bf16*)alloc((size_t)MM * 768 * 2);         // 157.3 MB
  bf16* attn = (bf16*)alloc((size_t)MM * 256 * 2);         // 52.4 MB
  bf16* Wt   = (bf16*)alloc((size_t)768 * 768 * 2);
  bf16* woB  = (bf16*)alloc((size_t)256 * 256 * 2);
  float* bias = (float*)alloc((size_t)HH * NN * NN * 4);
  int* adjm  = (int*)alloc((size_t)NN * NN * 4);

  hipLaunchKernelGGL(k_prep_xpad, dim3(13824), dim3(256), 0, stream, x, xpad);
  hipLaunchKernelGGL(k_prep_misc, dim3(512), dim3(256), 0, stream,
                     wq, wk, wv, rel, lb, wo, adj, Wt, woB, bias, adjm);
  hipLaunchKernelGGL(k_qkv_gemm, dim3(800, 6), dim3(256), 0, stream, xpad, Wt, conv);
  hipLaunchKernelGGL(k_attn, dim3(4096), dim3(256), 0, stream,
                     conv, x, gq, bq, gk, bk, gv, bv, bias, adjm, attn);
  hipLaunchKernelGGL(k_outproj, dim3(800, 2), dim3(256), 0, stream, attn, woB, bo, out);
}

// Round 3
// 612.977 us; speedup vs baseline: 1.2099x; 1.2099x over previous
//
#include <hip/hip_runtime.h>

// ---------- problem constants ----------
#define BB 4096
#define NN 25
#define DD 256
#define HH 8
#define DKH 32
#define MM (BB*NN)          // 102400

typedef __bf16 bf16;
typedef bf16 bf16x8 __attribute__((ext_vector_type(8)));
typedef bf16 bf16x4 __attribute__((ext_vector_type(4)));
typedef float f32x4 __attribute__((ext_vector_type(4)));
typedef _Float16 h16;
typedef h16 h16x2 __attribute__((ext_vector_type(2)));
typedef h16 h16x4 __attribute__((ext_vector_type(4)));
typedef h16 h16x8 __attribute__((ext_vector_type(8)));

// async global->LDS, 16B per lane, LDS dest = wave-uniform base + lane*16
__device__ __forceinline__ void async_load16(const void* g, void* l) {
  __builtin_amdgcn_global_load_lds(
      (const __attribute__((address_space(1))) unsigned int*)g,
      (__attribute__((address_space(3))) unsigned int*)l, 16, 0, 0);
}

// ---------- prep: padded bf16 x  x_pad[b][j][d], j in [0,27): j=0,26 zero, else x[b][j-1][d]
__global__ __launch_bounds__(256) void k_prep_xpad(const float* __restrict__ x,
                                                   bf16* __restrict__ xpad) {
  int idx = (blockIdx.x * 256 + threadIdx.x) * 8;
  const int total = BB * 27 * 256;
  if (idx >= total) return;
  int b = idx / (27 * 256);
  int rem = idx - b * 27 * 256;
  int j = rem >> 8;
  int d = rem & 255;
  bf16x8 o;
  if (j >= 1 && j <= 25) {
    const float* src = x + ((b * 25 + (j - 1)) * 256 + d);
    #pragma unroll
    for (int t = 0; t < 8; ++t) o[t] = (bf16)src[t];
  } else {
    #pragma unroll
    for (int t = 0; t < 8; ++t) o[t] = (bf16)0.0f;
  }
  *(bf16x8*)(xpad + idx) = o;
}

// ---------- prep: Wt[768][768] (B^T for qkv gemm), wo bf16, masked bias mb[h][i][32] ----------
__global__ __launch_bounds__(256) void k_prep_misc(
    const float* __restrict__ wq, const float* __restrict__ wk, const float* __restrict__ wv,
    const float* __restrict__ rel, const float* __restrict__ lb, const float* __restrict__ wo,
    const void* __restrict__ adj_raw,
    bf16* __restrict__ Wt, bf16* __restrict__ woB, float* __restrict__ mb) {
  const int NWT = 768 * 768;
  const int NWO = 256 * 256;
  const int NMB = HH * NN * 32;
  const int total = NWT + NWO + NMB;
  for (int i = blockIdx.x * blockDim.x + threadIdx.x; i < total; i += gridDim.x * blockDim.x) {
    if (i < NWT) {
      int j = i / 768, kk = i - j * 768;
      int proj = j >> 8, jo = j & 255;
      int tap = kk >> 8, di = kk & 255;
      const float* w = (proj == 0) ? wq : ((proj == 1) ? wk : wv);
      Wt[i] = (bf16)w[(jo * 256 + di) * 3 + tap];   // w[d_out][d_in][tap]
    } else if (i < NWT + NWO) {
      int t = i - NWT;
      woB[t] = (bf16)wo[t];                          // wo[j][d] is already B^T layout
    } else {
      int t = i - NWT - NWO;
      int pair = t >> 5;          // h*25 + i
      int m = t & 31;
      int h = pair / 25, ii = pair - h * 25;
      float v = -1e30f;
      if (m < 25) {
        // detect whether adj is uint8 (bool) or int32
        const unsigned char* bytes = (const unsigned char*)adj_raw;
        bool u8 = false;
        for (int s = 0; s < 625; ++s) {
          if ((s & 3) && bytes[s]) { u8 = true; break; }
        }
        int amask = u8 ? (bytes[ii * 25 + m] ? 1 : 0)
                       : (((const int*)adj_raw)[ii * 25 + m] ? 1 : 0);
        if (amask)
          v = rel[(ii - m + 24) * HH + h] + lb[h * 625 + ii * 25 + m];
      }
      mb[t] = v;
    }
  }
}

// ---------- QKV GEMM: C[102400][768] = A_gather[102400][768] * Wt^T, bf16 MFMA ----------
__global__ __launch_bounds__(256) void k_qkv_gemm(const bf16* __restrict__ xpad,
                                                  const bf16* __restrict__ Wt,
                                                  bf16* __restrict__ conv) {
  __shared__ bf16 As[128 * 32];
  __shared__ bf16 Bs[128 * 32];
  const int m0 = blockIdx.x * 128;
  const int n0 = blockIdx.y * 128;
  const int tid = threadIdx.x;
  const int wave = tid >> 6, lane = tid & 63;
  const int quad = lane >> 4, t16 = lane & 15;
  const int wr = wave >> 1, wc = wave & 1;

  f32x4 acc[4][4];
  #pragma unroll
  for (int i = 0; i < 4; ++i)
    #pragma unroll
    for (int j = 0; j < 4; ++j) acc[i][j] = (f32x4){0.f, 0.f, 0.f, 0.f};

  const bf16* baseA[2];
  const bf16* baseB[2];
  #pragma unroll
  for (int r = 0; r < 2; ++r) {
    int c = r * 256 + wave * 64 + lane;
    int row = c >> 2, sub = c & 3;
    int gm = m0 + row;
    int b = gm / 25;
    int n = gm - b * 25;
    baseA[r] = xpad + (b * 27 + n) * 256 + sub * 8;
    baseB[r] = Wt + (n0 + row) * 768 + sub * 8;
  }

  for (int ks = 0; ks < 768; ks += 32) {
    const int tap = ks >> 8;
    const int d0 = ks & 255;
    #pragma unroll
    for (int r = 0; r < 2; ++r)
      async_load16(baseA[r] + tap * 256 + d0, As + (r * 256 + wave * 64) * 8);
    #pragma unroll
    for (int r = 0; r < 2; ++r)
      async_load16(baseB[r] + ks, Bs + (r * 256 + wave * 64) * 8);
    asm volatile("s_waitcnt vmcnt(0)" ::: "memory");
    __syncthreads();

    bf16x8 af[4], bfr[4];
    #pragma unroll
    for (int i = 0; i < 4; ++i)
      af[i] = *(const bf16x8*)(As + (wr * 64 + i * 16 + t16) * 32 + quad * 8);
    #pragma unroll
    for (int j = 0; j < 4; ++j)
      bfr[j] = *(const bf16x8*)(Bs + (wc * 64 + j * 16 + t16) * 32 + quad * 8);
    #pragma unroll
    for (int i = 0; i < 4; ++i)
      #pragma unroll
      for (int j = 0; j < 4; ++j)
        acc[i][j] = __builtin_amdgcn_mfma_f32_16x16x32_bf16(af[i], bfr[j], acc[i][j], 0, 0, 0);
    __syncthreads();
  }

  #pragma unroll
  for (int i = 0; i < 4; ++i)
    #pragma unroll
    for (int j = 0; j < 4; ++j) {
      int col = n0 + wc * 64 + j * 16 + t16;
      #pragma unroll
      for (int r = 0; r < 4; ++r) {
        int rowm = m0 + wr * 64 + i * 16 + quad * 4 + r;
        conv[rowm * 768 + col] = (bf16)acc[i][j][r];
      }
    }
}

// ---------- LN + residual, in-place: conv row-slice (bf16) -> f16 at same byte offsets ----------
__global__ __launch_bounds__(256) void k_ln(bf16* __restrict__ conv, const float* __restrict__ x,
    const float* __restrict__ gq, const float* __restrict__ bq,
    const float* __restrict__ gk, const float* __restrict__ bk,
    const float* __restrict__ gv, const float* __restrict__ bv) {
  const int wave = threadIdx.x >> 6, lane = threadIdx.x & 63;
  const int g = blockIdx.x * 4 + wave;          // < 307200 exactly
  const int b = g / 75;
  const int rem = g - b * 75;
  const int p = rem / 25;
  const int n = rem - p * 25;
  const size_t off = ((size_t)(b * 25 + n)) * 768 + p * 256 + lane * 4;

  bf16x4 cv = *(const bf16x4*)(conv + off);
  float v0 = (float)cv[0], v1 = (float)cv[1], v2 = (float)cv[2], v3 = (float)cv[3];
  float s = v0 + v1 + v2 + v3;
  float ss = v0 * v0 + v1 * v1 + v2 * v2 + v3 * v3;
  #pragma unroll
  for (int o = 32; o; o >>= 1) {
    s += __shfl_xor(s, o);
    ss += __shfl_xor(ss, o);
  }
  float mu = s * (1.0f / 256.0f);
  float var = ss * (1.0f / 256.0f) - mu * mu;
  float rs = rsqrtf(var + 1e-5f);
  const float* gsel = (p == 0) ? gq : ((p == 1) ? gk : gv);
  const float* bsel = (p == 0) ? bq : ((p == 1) ? bk : bv);
  const int dbase = lane * 4;
  f32x4 gg = *(const f32x4*)(gsel + dbase);
  f32x4 b2 = *(const f32x4*)(bsel + dbase);
  f32x4 xv = *(const f32x4*)(x + ((size_t)(b * 25 + n)) * 256 + dbase);
  h16x4 o;
  o[0] = (h16)((v0 - mu) * rs * gg[0] + b2[0] + xv[0]);
  o[1] = (h16)((v1 - mu) * rs * gg[1] + b2[1] + xv[1]);
  o[2] = (h16)((v2 - mu) * rs * gg[2] + b2[2] + xv[2]);
  o[3] = (h16)((v3 - mu) * rs * gg[3] + b2[3] + xv[3]);
  *(h16x4*)((h16*)conv + off) = o;
}

// ---------- per-batch masked attention (reads f16 q,k,v from conv buffer) ----------
__global__ __launch_bounds__(256, 4) void k_attn2(
    const h16* __restrict__ convh, const float* __restrict__ mb,
    bf16* __restrict__ attnout) {
  __shared__ h16 Ks[25 * 256 + 256];   // small slack for the clamped over-stage
  __shared__ h16 Vs[25 * 256 + 256];
  const int b = blockIdx.x;
  const int tid = threadIdx.x;
  const int wave = tid >> 6, lane = tid & 63;

  // stage k (p=1) and v (p=2) rows: 25 rows x 256 f16 each
  const h16* base = convh + ((size_t)b * 25) * 768;
  for (int r = wave; r < 13; r += 4) {
    int idx = r * 64 + lane;                 // [0, 832)
    int n = idx >> 5;
    if (n > 24) n = 24;                      // clamp: slots >= 800 unused
    int d0 = (idx & 31) * 8;
    async_load16(base + (size_t)n * 768 + 256 + d0, Ks + r * 512);
    async_load16(base + (size_t)n * 768 + 512 + d0, Vs + r * 512);
  }
  asm volatile("s_waitcnt vmcnt(0)" ::: "memory");
  __syncthreads();

  if (tid < HH * NN) {
    const int h = tid / 25;
    const int i = tid - h * 25;

    // q fragment: 32 f16 from global (per-lane, L2-cached), as 16 packed pairs
    h16x2 qv[16];
    const h16x2* qp = (const h16x2*)(base + (size_t)i * 768 + h * 32);
    #pragma unroll
    for (int c = 0; c < 16; ++c) qv[c] = qp[c];

    // masked bias row
    float mrow[28];
    const float* mbp = mb + (h * 25 + i) * 32;
    #pragma unroll
    for (int c = 0; c < 7; ++c) *(f32x4*)(mrow + c * 4) = *(const f32x4*)(mbp + c * 4);

    const float scale = 0.17677669529663687f;  // 1/sqrt(32)
    float sc[25];
    #pragma unroll
    for (int m = 0; m < 25; ++m) {
      const h16x2* kr = (const h16x2*)(Ks + m * 256 + h * 32);
      float d = 0.f;
      #pragma unroll
      for (int c = 0; c < 16; ++c)
        d = __builtin_amdgcn_fdot2(qv[c], kr[c], d, false);
      sc[m] = d * scale + mrow[m];
    }

    float mx = sc[0];
    #pragma unroll
    for (int m = 1; m < 25; ++m) mx = fmaxf(mx, sc[m]);
    float sum = 0.f;
    #pragma unroll
    for (int m = 0; m < 25; ++m) { sc[m] = __expf(sc[m] - mx); sum += sc[m]; }
    const float inv = 1.0f / sum;

    h16x2 acc[16];
    #pragma unroll
    for (int j = 0; j < 16; ++j) acc[j] = (h16x2){(h16)0.f, (h16)0.f};
    #pragma unroll
    for (int m = 0; m < 25; ++m) {
      h16 w = (h16)(sc[m] * inv);
      h16x2 wp = {w, w};
      const h16x2* vr = (const h16x2*)(Vs + m * 256 + h * 32);
      #pragma unroll
      for (int j = 0; j < 16; ++j)
        acc[j] = wp * vr[j] + acc[j];   // v_pk_fma_f16
    }

    bf16* dst = attnout + ((size_t)b * 25 + i) * 256 + h * 32;
    #pragma unroll
    for (int c = 0; c < 4; ++c) {
      bf16x8 o;
      #pragma unroll
      for (int j = 0; j < 4; ++j) {
        o[2 * j]     = (bf16)(float)acc[c * 4 + j][0];
        o[2 * j + 1] = (bf16)(float)acc[c * 4 + j][1];
      }
      *(bf16x8*)(dst + c * 8) = o;
    }
  }
}

// ---------- output projection: out = attn @ wo^T + bo (f32 out) ----------
__global__ __launch_bounds__(256) void k_outproj(const bf16* __restrict__ attn,
                                                 const bf16* __restrict__ woB,
                                                 const float* __restrict__ bo,
                                                 float* __restrict__ out) {
  __shared__ bf16 As[128 * 32];
  __shared__ bf16 Bs[128 * 32];
  const int m0 = blockIdx.x * 128;
  const int n0 = blockIdx.y * 128;
  const int tid = threadIdx.x;
  const int wave = tid >> 6, lane = tid & 63;
  const int quad = lane >> 4, t16 = lane & 15;
  const int wr = wave >> 1, wc = wave & 1;

  f32x4 acc[4][4];
  #pragma unroll
  for (int i = 0; i < 4; ++i)
    #pragma unroll
    for (int j = 0; j < 4; ++j) acc[i][j] = (f32x4){0.f, 0.f, 0.f, 0.f};

  const bf16* baseA[2];
  const bf16* baseB[2];
  #pragma unroll
  for (int r = 0; r < 2; ++r) {
    int c = r * 256 + wave * 64 + lane;
    int row = c >> 2, sub = c & 3;
    baseA[r] = attn + (m0 + row) * 256 + sub * 8;
    baseB[r] = woB + (n0 + row) * 256 + sub * 8;
  }

  for (int ks = 0; ks < 256; ks += 32) {
    #pragma unroll
    for (int r = 0; r < 2; ++r)
      async_load16(baseA[r] + ks, As + (r * 256 + wave * 64) * 8);
    #pragma unroll
    for (int r = 0; r < 2; ++r)
      async_load16(baseB[r] + ks, Bs + (r * 256 + wave * 64) * 8);
    asm volatile("s_waitcnt vmcnt(0)" ::: "memory");
    __syncthreads();

    bf16x8 af[4], bfr[4];
    #pragma unroll
    for (int i = 0; i < 4; ++i)
      af[i] = *(const bf16x8*)(As + (wr * 64 + i * 16 + t16) * 32 + quad * 8);
    #pragma unroll
    for (int j = 0; j < 4; ++j)
      bfr[j] = *(const bf16x8*)(Bs + (wc * 64 + j * 16 + t16) * 32 + quad * 8);
    #pragma unroll
    for (int i = 0; i < 4; ++i)
      #pragma unroll
      for (int j = 0; j < 4; ++j)
        acc[i][j] = __builtin_amdgcn_mfma_f32_16x16x32_bf16(af[i], bfr[j], acc[i][j], 0, 0, 0);
    __syncthreads();
  }

  #pragma unroll
  for (int j = 0; j < 4; ++j) {
    int col = n0 + wc * 64 + j * 16 + t16;
    float bb = bo[col];
    #pragma unroll
    for (int i = 0; i < 4; ++i)
      #pragma unroll
      for (int r = 0; r < 4; ++r) {
        int rowm = m0 + wr * 64 + i * 16 + quad * 4 + r;
        out[rowm * 256 + col] = acc[i][j][r] + bb;
      }
  }
}

extern "C" void kernel_launch(void* const* d_in, const int* in_sizes, int n_in,
                              void* d_out, int out_size, void* d_ws, size_t ws_size,
                              hipStream_t stream) {
  (void)in_sizes; (void)n_in; (void)out_size; (void)ws_size;
  const float* x  = (const float*)d_in[0];
  const void*  adj = d_in[1];
  const float* wq = (const float*)d_in[2];
  const float* wk = (const float*)d_in[3];
  const float* wv = (const float*)d_in[4];
  const float* gq = (const float*)d_in[5];
  const float* bq = (const float*)d_in[6];
  const float* gk = (const float*)d_in[7];
  const float* bk = (const float*)d_in[8];
  const float* gv = (const float*)d_in[9];
  const float* bv = (const float*)d_in[10];
  const float* rel = (const float*)d_in[11];
  const float* lb = (const float*)d_in[12];
  const float* wo = (const float*)d_in[13];
  const float* bo = (const float*)d_in[14];
  float* out = (float*)d_out;

  char* ws = (char*)d_ws;
  size_t off = 0;
  auto alloc = [&](size_t bytes) -> void* {
    void* p = ws + off;
    off += (bytes + 255) & ~(size_t)255;
    return p;
  };
  bf16* xpad = (bf16*)alloc((size_t)BB * 27 * 256 * 2);    // 56.6 MB
  bf16* conv = (bf16*)alloc((size_t)MM * 768 * 2);         // 157.3 MB (qkv f16 in-place after k_ln)
  bf16* attn = (bf16*)alloc((size_t)MM * 256 * 2);         // 52.4 MB
  bf16* Wt   = (bf16*)alloc((size_t)768 * 768 * 2);
  bf16* woB  = (bf16*)alloc((size_t)256 * 256 * 2);
  float* mb  = (float*)alloc((size_t)HH * NN * 32 * 4);

  hipLaunchKernelGGL(k_prep_xpad, dim3(13824), dim3(256), 0, stream, x, xpad);
  hipLaunchKernelGGL(k_prep_misc, dim3(512), dim3(256), 0, stream,
                     wq, wk, wv, rel, lb, wo, adj, Wt, woB, mb);
  hipLaunchKernelGGL(k_qkv_gemm, dim3(800, 6), dim3(256), 0, stream, xpad, Wt, conv);
  hipLaunchKernelGGL(k_ln, dim3(76800), dim3(256), 0, stream,
                     conv, x, gq, bq, gk, bk, gv, bv);
  hipLaunchKernelGGL(k_attn2, dim3(4096), dim3(256), 0, stream,
                     (const h16*)conv, mb, attn);
  hipLaunchKernelGGL(k_outproj, dim3(800, 2), dim3(256), 0, stream, attn, woB, bo, out);
}

// Round 4
// 556.330 us; speedup vs baseline: 1.3331x; 1.1018x over previous
//
#include <hip/hip_runtime.h>

// ---------- problem constants ----------
#define BB 4096
#define NN 25
#define DD 256
#define HH 8
#define DKH 32
#define MM (BB*NN)          // 102400

typedef __bf16 bf16;
typedef bf16 bf16x8 __attribute__((ext_vector_type(8)));
typedef bf16 bf16x4 __attribute__((ext_vector_type(4)));
typedef float f32x4 __attribute__((ext_vector_type(4)));
typedef _Float16 h16;
typedef h16 h16x2 __attribute__((ext_vector_type(2)));
typedef h16 h16x4 __attribute__((ext_vector_type(4)));
typedef h16 h16x8 __attribute__((ext_vector_type(8)));

// async global->LDS, 16B per lane, LDS dest = wave-uniform base + lane*16
__device__ __forceinline__ void async_load16(const void* g, void* l) {
  __builtin_amdgcn_global_load_lds(
      (const __attribute__((address_space(1))) unsigned int*)g,
      (__attribute__((address_space(3))) unsigned int*)l, 16, 0, 0);
}

// ---------- prep: padded bf16 x  x_pad[b][j][d], j in [0,27): j=0,26 zero, else x[b][j-1][d]
__global__ __launch_bounds__(256) void k_prep_xpad(const float* __restrict__ x,
                                                   bf16* __restrict__ xpad) {
  int idx = (blockIdx.x * 256 + threadIdx.x) * 8;
  const int total = BB * 27 * 256;
  if (idx >= total) return;
  int b = idx / (27 * 256);
  int rem = idx - b * 27 * 256;
  int j = rem >> 8;
  int d = rem & 255;
  bf16x8 o;
  if (j >= 1 && j <= 25) {
    const float* src = x + ((b * 25 + (j - 1)) * 256 + d);
    #pragma unroll
    for (int t = 0; t < 8; ++t) o[t] = (bf16)src[t];
  } else {
    #pragma unroll
    for (int t = 0; t < 8; ++t) o[t] = (bf16)0.0f;
  }
  *(bf16x8*)(xpad + idx) = o;
}

// ---------- prep: Wt[768][768] (B^T for qkv gemm), wo bf16, masked bias mb[h][i][32] ----------
__global__ __launch_bounds__(256) void k_prep_misc(
    const float* __restrict__ wq, const float* __restrict__ wk, const float* __restrict__ wv,
    const float* __restrict__ rel, const float* __restrict__ lb, const float* __restrict__ wo,
    const void* __restrict__ adj_raw,
    bf16* __restrict__ Wt, bf16* __restrict__ woB, float* __restrict__ mb) {
  const int NWT = 768 * 768;
  const int NWO = 256 * 256;
  const int NMB = HH * NN * 32;
  const int total = NWT + NWO + NMB;
  for (int i = blockIdx.x * blockDim.x + threadIdx.x; i < total; i += gridDim.x * blockDim.x) {
    if (i < NWT) {
      int j = i / 768, kk = i - j * 768;
      int proj = j >> 8, jo = j & 255;
      int tap = kk >> 8, di = kk & 255;
      const float* w = (proj == 0) ? wq : ((proj == 1) ? wk : wv);
      Wt[i] = (bf16)w[(jo * 256 + di) * 3 + tap];   // w[d_out][d_in][tap]
    } else if (i < NWT + NWO) {
      int t = i - NWT;
      woB[t] = (bf16)wo[t];                          // wo[j][d] is already B^T layout
    } else {
      int t = i - NWT - NWO;
      int pair = t >> 5;          // h*25 + i
      int m = t & 31;
      int h = pair / 25, ii = pair - h * 25;
      float v = -1e30f;
      if (m < 25) {
        // detect whether adj is uint8 (bool) or int32
        const unsigned char* bytes = (const unsigned char*)adj_raw;
        bool u8 = false;
        for (int s = 0; s < 625; ++s) {
          if ((s & 3) && bytes[s]) { u8 = true; break; }
        }
        int amask = u8 ? (bytes[ii * 25 + m] ? 1 : 0)
                       : (((const int*)adj_raw)[ii * 25 + m] ? 1 : 0);
        if (amask)
          v = rel[(ii - m + 24) * HH + h] + lb[h * 625 + ii * 25 + m];
      }
      mb[t] = v;
    }
  }
}

// ---------- QKV GEMM: C[102400][768] = A_gather[102400][768] * Wt^T, bf16 MFMA ----------
// linear grid (4800), XCD-aware swizzle: the 6 n-siblings of an m-tile are
// consecutive in dispatch AND congruent mod 8 -> same XCD L2 re-serves the A-tile.
__global__ __launch_bounds__(256) void k_qkv_gemm(const bf16* __restrict__ xpad,
                                                  const bf16* __restrict__ Wt,
                                                  bf16* __restrict__ conv) {
  __shared__ bf16 As[128 * 32];
  __shared__ bf16 Bs[128 * 32];
  const int L = blockIdx.x;
  const int X = L & 7;
  const int t = L >> 3;                 // [0,600)
  const int n0 = (t % 6) * 128;
  const int m0 = (X + 8 * (t / 6)) * 128;   // Mi in [0,800), Mi%8==X
  const int tid = threadIdx.x;
  const int wave = tid >> 6, lane = tid & 63;
  const int quad = lane >> 4, t16 = lane & 15;
  const int wr = wave >> 1, wc = wave & 1;

  f32x4 acc[4][4];
  #pragma unroll
  for (int i = 0; i < 4; ++i)
    #pragma unroll
    for (int j = 0; j < 4; ++j) acc[i][j] = (f32x4){0.f, 0.f, 0.f, 0.f};

  const bf16* baseA[2];
  const bf16* baseB[2];
  #pragma unroll
  for (int r = 0; r < 2; ++r) {
    int c = r * 256 + wave * 64 + lane;
    int row = c >> 2, sub = c & 3;
    int gm = m0 + row;
    int b = gm / 25;
    int n = gm - b * 25;
    baseA[r] = xpad + (b * 27 + n) * 256 + sub * 8;
    baseB[r] = Wt + (n0 + row) * 768 + sub * 8;
  }

  for (int ks = 0; ks < 768; ks += 32) {
    const int tap = ks >> 8;
    const int d0 = ks & 255;
    #pragma unroll
    for (int r = 0; r < 2; ++r)
      async_load16(baseA[r] + tap * 256 + d0, As + (r * 256 + wave * 64) * 8);
    #pragma unroll
    for (int r = 0; r < 2; ++r)
      async_load16(baseB[r] + ks, Bs + (r * 256 + wave * 64) * 8);
    asm volatile("s_waitcnt vmcnt(0)" ::: "memory");
    __syncthreads();

    bf16x8 af[4], bfr[4];
    #pragma unroll
    for (int i = 0; i < 4; ++i)
      af[i] = *(const bf16x8*)(As + (wr * 64 + i * 16 + t16) * 32 + quad * 8);
    #pragma unroll
    for (int j = 0; j < 4; ++j)
      bfr[j] = *(const bf16x8*)(Bs + (wc * 64 + j * 16 + t16) * 32 + quad * 8);
    #pragma unroll
    for (int i = 0; i < 4; ++i)
      #pragma unroll
      for (int j = 0; j < 4; ++j)
        acc[i][j] = __builtin_amdgcn_mfma_f32_16x16x32_bf16(af[i], bfr[j], acc[i][j], 0, 0, 0);
    __syncthreads();
  }

  #pragma unroll
  for (int i = 0; i < 4; ++i)
    #pragma unroll
    for (int j = 0; j < 4; ++j) {
      int col = n0 + wc * 64 + j * 16 + t16;
      #pragma unroll
      for (int r = 0; r < 4; ++r) {
        int rowm = m0 + wr * 64 + i * 16 + quad * 4 + r;
        conv[rowm * 768 + col] = (bf16)acc[i][j][r];
      }
    }
}

// ---------- fused LN + residual + masked attention, one block per batch ----------
// stages the contiguous 25x768 bf16 qkv slab via global_load_lds, LayerNorms
// in-place to f16 (per-lane 8B->8B), then does the masked attention from LDS.
__global__ __launch_bounds__(256, 4) void k_attn3(
    const bf16* __restrict__ conv, const float* __restrict__ x,
    const float* __restrict__ gq, const float* __restrict__ bq,
    const float* __restrict__ gk, const float* __restrict__ bk,
    const float* __restrict__ gv, const float* __restrict__ bv,
    const float* __restrict__ mb, bf16* __restrict__ attnout) {
  __shared__ bf16 Cs[19456];     // 38912 B: 38 x 1024B chunks (25*768=19200 used)
  const int b = blockIdx.x;
  const int tid = threadIdx.x;
  const int wave = tid >> 6, lane = tid & 63;

  // blanket stage of the batch slab (contiguous 38400 B, over-staged to 38912 B)
  const char* slab = (const char*)(conv + (size_t)b * 19200);
  for (int c = wave; c < 38; c += 4)
    async_load16(slab + c * 1024 + lane * 16, (char*)Cs + c * 1024);
  asm volatile("s_waitcnt vmcnt(0)" ::: "memory");
  __syncthreads();

  // phase 1: LN + residual for 75 rows (node n, proj p), one wave per row
  for (int rowi = wave; rowi < 75; rowi += 4) {
    int n = rowi / 3;
    int p = rowi - n * 3;
    const int off = n * 768 + p * 256 + lane * 4;
    bf16x4 cv = *(const bf16x4*)(Cs + off);
    float v0 = (float)cv[0], v1 = (float)cv[1], v2 = (float)cv[2], v3 = (float)cv[3];
    float s = v0 + v1 + v2 + v3;
    float ss = v0 * v0 + v1 * v1 + v2 * v2 + v3 * v3;
    #pragma unroll
    for (int o = 32; o; o >>= 1) {
      s += __shfl_xor(s, o);
      ss += __shfl_xor(ss, o);
    }
    float mu = s * (1.0f / 256.0f);
    float var = ss * (1.0f / 256.0f) - mu * mu;
    float rs = rsqrtf(var + 1e-5f);
    const float* gsel = (p == 0) ? gq : ((p == 1) ? gk : gv);
    const float* bsel = (p == 0) ? bq : ((p == 1) ? bk : bv);
    const int dbase = lane * 4;
    f32x4 gg = *(const f32x4*)(gsel + dbase);
    f32x4 b2 = *(const f32x4*)(bsel + dbase);
    f32x4 xv = *(const f32x4*)(x + ((size_t)(b * 25 + n)) * 256 + dbase);
    h16x4 o;
    o[0] = (h16)((v0 - mu) * rs * gg[0] + b2[0] + xv[0]);
    o[1] = (h16)((v1 - mu) * rs * gg[1] + b2[1] + xv[1]);
    o[2] = (h16)((v2 - mu) * rs * gg[2] + b2[2] + xv[2]);
    o[3] = (h16)((v3 - mu) * rs * gg[3] + b2[3] + xv[3]);
    *(h16x4*)((h16*)Cs + off) = o;   // in-place bf16 -> f16, per-lane 8B
  }
  __syncthreads();

  // phase 2: one lane per (head, query-node)
  const h16* Ch = (const h16*)Cs;
  if (tid < HH * NN) {
    const int h = tid / 25;
    const int i = tid - h * 25;

    h16x2 qv[16];
    const h16x2* qp = (const h16x2*)(Ch + i * 768 + h * 32);
    #pragma unroll
    for (int c = 0; c < 16; ++c) qv[c] = qp[c];

    float mrow[28];
    const float* mbp = mb + (h * 25 + i) * 32;
    #pragma unroll
    for (int c = 0; c < 7; ++c) *(f32x4*)(mrow + c * 4) = *(const f32x4*)(mbp + c * 4);

    const float scale = 0.17677669529663687f;  // 1/sqrt(32)
    float sc[25];
    #pragma unroll
    for (int m = 0; m < 25; ++m) {
      const h16x2* kr = (const h16x2*)(Ch + m * 768 + 256 + h * 32);
      float d = 0.f;
      #pragma unroll
      for (int c = 0; c < 16; ++c)
        d = __builtin_amdgcn_fdot2(qv[c], kr[c], d, false);
      sc[m] = d * scale + mrow[m];
    }

    float mx = sc[0];
    #pragma unroll
    for (int m = 1; m < 25; ++m) mx = fmaxf(mx, sc[m]);
    float sum = 0.f;
    #pragma unroll
    for (int m = 0; m < 25; ++m) { sc[m] = __expf(sc[m] - mx); sum += sc[m]; }
    const float inv = 1.0f / sum;

    h16x2 acc[16];
    #pragma unroll
    for (int j = 0; j < 16; ++j) acc[j] = (h16x2){(h16)0.f, (h16)0.f};
    #pragma unroll
    for (int m = 0; m < 25; ++m) {
      h16 w = (h16)(sc[m] * inv);
      h16x2 wp = {w, w};
      const h16x2* vr = (const h16x2*)(Ch + m * 768 + 512 + h * 32);
      #pragma unroll
      for (int j = 0; j < 16; ++j)
        acc[j] = wp * vr[j] + acc[j];   // v_pk_fma_f16
    }

    bf16* dst = attnout + ((size_t)b * 25 + i) * 256 + h * 32;
    #pragma unroll
    for (int c = 0; c < 4; ++c) {
      bf16x8 o;
      #pragma unroll
      for (int j = 0; j < 4; ++j) {
        o[2 * j]     = (bf16)(float)acc[c * 4 + j][0];
        o[2 * j + 1] = (bf16)(float)acc[c * 4 + j][1];
      }
      *(bf16x8*)(dst + c * 8) = o;
    }
  }
}

// ---------- output projection: out = attn @ wo^T + bo (f32 out), swizzled grid ----------
__global__ __launch_bounds__(256) void k_outproj(const bf16* __restrict__ attn,
                                                 const bf16* __restrict__ woB,
                                                 const float* __restrict__ bo,
                                                 float* __restrict__ out) {
  __shared__ bf16 As[128 * 32];
  __shared__ bf16 Bs[128 * 32];
  const int L = blockIdx.x;
  const int X = L & 7;
  const int t = L >> 3;                  // [0,200)
  const int n0 = (t & 1) * 128;
  const int m0 = (X + 8 * (t >> 1)) * 128;
  const int tid = threadIdx.x;
  const int wave = tid >> 6, lane = tid & 63;
  const int quad = lane >> 4, t16 = lane & 15;
  const int wr = wave >> 1, wc = wave & 1;

  f32x4 acc[4][4];
  #pragma unroll
  for (int i = 0; i < 4; ++i)
    #pragma unroll
    for (int j = 0; j < 4; ++j) acc[i][j] = (f32x4){0.f, 0.f, 0.f, 0.f};

  const bf16* baseA[2];
  const bf16* baseB[2];
  #pragma unroll
  for (int r = 0; r < 2; ++r) {
    int c = r * 256 + wave * 64 + lane;
    int row = c >> 2, sub = c & 3;
    baseA[r] = attn + (m0 + row) * 256 + sub * 8;
    baseB[r] = woB + (n0 + row) * 256 + sub * 8;
  }

  for (int ks = 0; ks < 256; ks += 32) {
    #pragma unroll
    for (int r = 0; r < 2; ++r)
      async_load16(baseA[r] + ks, As + (r * 256 + wave * 64) * 8);
    #pragma unroll
    for (int r = 0; r < 2; ++r)
      async_load16(baseB[r] + ks, Bs + (r * 256 + wave * 64) * 8);
    asm volatile("s_waitcnt vmcnt(0)" ::: "memory");
    __syncthreads();

    bf16x8 af[4], bfr[4];
    #pragma unroll
    for (int i = 0; i < 4; ++i)
      af[i] = *(const bf16x8*)(As + (wr * 64 + i * 16 + t16) * 32 + quad * 8);
    #pragma unroll
    for (int j = 0; j < 4; ++j)
      bfr[j] = *(const bf16x8*)(Bs + (wc * 64 + j * 16 + t16) * 32 + quad * 8);
    #pragma unroll
    for (int i = 0; i < 4; ++i)
      #pragma unroll
      for (int j = 0; j < 4; ++j)
        acc[i][j] = __builtin_amdgcn_mfma_f32_16x16x32_bf16(af[i], bfr[j], acc[i][j], 0, 0, 0);
    __syncthreads();
  }

  #pragma unroll
  for (int j = 0; j < 4; ++j) {
    int col = n0 + wc * 64 + j * 16 + t16;
    float bb = bo[col];
    #pragma unroll
    for (int i = 0; i < 4; ++i)
      #pragma unroll
      for (int r = 0; r < 4; ++r) {
        int rowm = m0 + wr * 64 + i * 16 + quad * 4 + r;
        out[rowm * 256 + col] = acc[i][j][r] + bb;
      }
  }
}

extern "C" void kernel_launch(void* const* d_in, const int* in_sizes, int n_in,
                              void* d_out, int out_size, void* d_ws, size_t ws_size,
                              hipStream_t stream) {
  (void)in_sizes; (void)n_in; (void)out_size; (void)ws_size;
  const float* x  = (const float*)d_in[0];
  const void*  adj = d_in[1];
  const float* wq = (const float*)d_in[2];
  const float* wk = (const float*)d_in[3];
  const float* wv = (const float*)d_in[4];
  const float* gq = (const float*)d_in[5];
  const float* bq = (const float*)d_in[6];
  const float* gk = (const float*)d_in[7];
  const float* bk = (const float*)d_in[8];
  const float* gv = (const float*)d_in[9];
  const float* bv = (const float*)d_in[10];
  const float* rel = (const float*)d_in[11];
  const float* lb = (const float*)d_in[12];
  const float* wo = (const float*)d_in[13];
  const float* bo = (const float*)d_in[14];
  float* out = (float*)d_out;

  char* ws = (char*)d_ws;
  size_t off = 0;
  auto alloc = [&](size_t bytes) -> void* {
    void* p = ws + off;
    off += (bytes + 255) & ~(size_t)255;
    return p;
  };
  bf16* xpad = (bf16*)alloc((size_t)BB * 27 * 256 * 2);    // 56.6 MB
  bf16* conv = (bf16*)alloc((size_t)MM * 768 * 2);         // 157.3 MB
  bf16* attn = (bf16*)alloc((size_t)MM * 256 * 2);         // 52.4 MB
  bf16* Wt   = (bf16*)alloc((size_t)768 * 768 * 2);
  bf16* woB  = (bf16*)alloc((size_t)256 * 256 * 2);
  float* mb  = (float*)alloc((size_t)HH * NN * 32 * 4);

  hipLaunchKernelGGL(k_prep_xpad, dim3(13824), dim3(256), 0, stream, x, xpad);
  hipLaunchKernelGGL(k_prep_misc, dim3(512), dim3(256), 0, stream,
                     wq, wk, wv, rel, lb, wo, adj, Wt, woB, mb);
  hipLaunchKernelGGL(k_qkv_gemm, dim3(4800), dim3(256), 0, stream, xpad, Wt, conv);
  hipLaunchKernelGGL(k_attn3, dim3(4096), dim3(256), 0, stream,
                     conv, x, gq, bq, gk, bk, gv, bv, mb, attn);
  hipLaunchKernelGGL(k_outproj, dim3(1600), dim3(256), 0, stream, attn, woB, bo, out);
}